// Round 23
// baseline (130.014 us; speedup 1.0000x reference)
//
#include <hip/hip_runtime.h>

typedef unsigned short u16;
typedef unsigned int u32;
typedef u16 u16x4 __attribute__((ext_vector_type(4)));
typedef u16 u16x8 __attribute__((ext_vector_type(8)));
typedef u32 u32x4 __attribute__((ext_vector_type(4)));
typedef float f32x4 __attribute__((ext_vector_type(4)));
typedef float f32x16 __attribute__((ext_vector_type(16)));
typedef __bf16 bf16x2 __attribute__((ext_vector_type(2)));
typedef __bf16 bf16x8 __attribute__((ext_vector_type(8)));

#define GLOAD16(gp, lp)                                             \
  __builtin_amdgcn_global_load_lds(                                 \
      (const __attribute__((address_space(1))) void*)(gp),          \
      (__attribute__((address_space(3))) void*)(lp), 16, 0, 0)

__device__ __forceinline__ u16 f2bf(float f) {
  unsigned int u = __builtin_bit_cast(unsigned int, f);
  u += 0x7FFFu + ((u >> 16) & 1u);
  return (u16)(u >> 16);
}
__device__ __forceinline__ float bf2f(u16 h) {
  return __builtin_bit_cast(float, (u32)h << 16);
}

// ------------------------------------------- all f32->bf16 converts, 1 launch
__global__ __launch_bounds__(256) void f2ball_kernel(const float* __restrict__ x,
    const float* __restrict__ w0, const float* __restrict__ w1,
    const float* __restrict__ w2, const float* __restrict__ w3,
    u16* __restrict__ xb, u16* __restrict__ wb) {
  int g = blockIdx.x * 256 + threadIdx.x;
  const float* s;
  u16* d;
  size_t off;
  if (g < 1048576) {
    s = x; d = xb; off = (size_t)g * 4;
  } else {
    int wi = g - 1048576;
    int sel = wi >> 18;
    int r = wi & 262143;
    s = (sel == 0) ? w0 : ((sel == 1) ? w1 : ((sel == 2) ? w2 : w3));
    d = wb + (size_t)sel * 1048576;
    off = (size_t)r * 4;
  }
  f32x4 v = *(const f32x4*)(s + off);
  u16x4 o;
  o[0] = f2bf(v[0]); o[1] = f2bf(v[1]); o[2] = f2bf(v[2]); o[3] = f2bf(v[3]);
  *(u16x4*)(d + off) = o;
}

// --------------------------------------------- NT GEMM core: C = A * W^T
// 128x128 tile, BK=32, 256 thr (4 waves). 3-buffer counted-vmcnt pipeline.
// SWAP=false: acc[m][n][r] = C[row=bm0+wr*64+m*16+lk*4+r][col=bn0+wc*64+n*16+lr]
// SWAP=true : acc[m][n][r] = C[row=bm0+wr*64+m*16+lr][col=bn0+wc*64+n*16+lk*4+r]
template <bool SWAP>
__device__ __forceinline__ void gemm_core(const u16* __restrict__ A,
                                          const u16* __restrict__ W,
                                          int bm0, int bn0,
                                          u16* ldsA, u16* ldsB,
                                          f32x4 acc[4][4]) {
  const int tid = threadIdx.x;
  const int l = tid & 63;
  const int lr = l & 15, lk = l >> 4;
  const int w = tid >> 6;
  const int wr = w >> 1, wc = w & 1;
  const int srow = tid >> 2, sko = (tid & 3) << 3;
  auto stage = [&](int kt, int buf) {  // 4 VMEM loads per thread
#pragma unroll
    for (int it = 0; it < 2; ++it) {
      int row = it * 64 + srow;
      GLOAD16(A + (size_t)(bm0 + row) * 1024 + kt * 32 + sko,
              ldsA + buf * 4096 + (it * 256 + tid) * 8);
      GLOAD16(W + (size_t)(bn0 + row) * 1024 + kt * 32 + sko,
              ldsB + buf * 4096 + (it * 256 + tid) * 8);
    }
  };
  stage(0, 0);
  stage(1, 1);
  int cur = 0, nx2 = 2;
  for (int kt = 0; kt < 32; ++kt) {
    if (kt < 31) asm volatile("s_waitcnt vmcnt(4)" ::: "memory");
    else         asm volatile("s_waitcnt vmcnt(0)" ::: "memory");
    __builtin_amdgcn_s_barrier();
    __builtin_amdgcn_sched_barrier(0);
    if (kt + 2 < 32) stage(kt + 2, nx2);
    const u16* lA = ldsA + cur * 4096;
    const u16* lB = ldsB + cur * 4096;
    bf16x8 af[4], bfr[4];
#pragma unroll
    for (int m = 0; m < 4; ++m)
      af[m] = *(const bf16x8*)(lA + (wr * 64 + m * 16 + lr) * 32 + lk * 8);
#pragma unroll
    for (int n = 0; n < 4; ++n)
      bfr[n] = *(const bf16x8*)(lB + (wc * 64 + n * 16 + lr) * 32 + lk * 8);
#pragma unroll
    for (int m = 0; m < 4; ++m)
#pragma unroll
      for (int n = 0; n < 4; ++n) {
        if (SWAP)
          acc[m][n] = __builtin_amdgcn_mfma_f32_16x16x32_bf16(bfr[n], af[m], acc[m][n], 0, 0, 0);
        else
          acc[m][n] = __builtin_amdgcn_mfma_f32_16x16x32_bf16(af[m], bfr[n], acc[m][n], 0, 0, 0);
      }
    cur = (cur == 2) ? 0 : cur + 1;
    nx2 = (nx2 == 2) ? 0 : nx2 + 1;
  }
}

// --------------------------------------------- fused QKV projection
// z=0: Q -> Qb rows (swapped core, u16x4 stores); z=1: K likewise;
// z=2: V -> V-frag (unswapped core, original epilogue).
__global__ __launch_bounds__(256) void qkv_gemm(const u16* __restrict__ xb,
    const u16* __restrict__ wq, const u16* __restrict__ wk, const u16* __restrict__ wv,
    const float* __restrict__ bq, const float* __restrict__ bk, const float* __restrict__ bv,
    u16* __restrict__ Qb, u16* __restrict__ Kb, u16* __restrict__ Vf) {
  __shared__ u16 ldsA[3 * 4096];
  __shared__ u16 ldsB[3 * 4096];
  const int z = blockIdx.z;
  const u16* W = (z == 0) ? wq : ((z == 1) ? wk : wv);
  const float* bias = (z == 0) ? bq : ((z == 1) ? bk : bv);
  const int bm0 = blockIdx.x * 128, bn0 = blockIdx.y * 128;
  const f32x4 zf = {0.f, 0.f, 0.f, 0.f};
  f32x4 acc[4][4];
#pragma unroll
  for (int m = 0; m < 4; ++m)
#pragma unroll
    for (int n = 0; n < 4; ++n) acc[m][n] = zf;
  const int tid = threadIdx.x, l = tid & 63, lr = l & 15, lk = l >> 4;
  const int w = tid >> 6, wr = w >> 1, wc = w & 1;
  if (z < 2) {
    gemm_core<true>(xb, W, bm0, bn0, ldsA, ldsB, acc);
    u16* outp = z ? Kb : Qb;
#pragma unroll
    for (int n = 0; n < 4; ++n) {
      f32x4 bv4 = *(const f32x4*)&bias[bn0 + wc * 64 + n * 16 + lk * 4];
#pragma unroll
      for (int m = 0; m < 4; ++m) {
        int row = bm0 + wr * 64 + m * 16 + lr;
        int col = bn0 + wc * 64 + n * 16 + lk * 4;
        u16x4 o;
#pragma unroll
        for (int r = 0; r < 4; ++r) o[r] = f2bf(acc[m][n][r] + bv4[r]);
        *(u16x4*)(outp + (size_t)row * 1024 + col) = o;
      }
    }
  } else {
    gemm_core<false>(xb, W, bm0, bn0, ldsA, ldsB, acc);
    float bcol[4];
#pragma unroll
    for (int n = 0; n < 4; ++n) bcol[n] = bias[bn0 + wc * 64 + n * 16 + lr];
#pragma unroll
    for (int m = 0; m < 4; ++m)
#pragma unroll
      for (int n = 0; n < 4; ++n) {
        int row = bm0 + wr * 64 + m * 16 + lk * 4;   // key base (r = 0..3)
        int col = bn0 + wc * 64 + n * 16 + lr;
        int b = row >> 11, sf = row & 2047, hh = col >> 6, hd = col & 63;
        int t = sf >> 6, kin = sf & 63;
        int ks = kin >> 4, hiv = (kin >> 3) & 1, j0 = kin & 7;
        int vhalf = hd >> 5, lq = hd & 31;
        u16x4 o;
#pragma unroll
        for (int r = 0; r < 4; ++r) o[r] = f2bf(acc[m][n][r] + bcol[n]);
        size_t addr = (size_t)(b * 16 + hh) * 131072 +
                      (size_t)(((t * 4 + ks) * 2 + vhalf)) * 512 +
                      ((hiv << 5) + lq) * 8 + j0;
        *(u16x4*)(Vf + addr) = o;
      }
  }
}

// --------------------------------------------- output projection, 64x128 tile
__global__ __launch_bounds__(256) void proj_gemm(const u16* __restrict__ ctx,
    const u16* __restrict__ wo, const float* __restrict__ bo, float* __restrict__ out) {
  __shared__ u16 ldsA[3 * 2048];
  __shared__ u16 ldsB[3 * 4096];
  const int bm0 = blockIdx.x * 64, bn0 = blockIdx.y * 128;
  const f32x4 zf = {0.f, 0.f, 0.f, 0.f};
  f32x4 acc[2][4];
#pragma unroll
  for (int m = 0; m < 2; ++m)
#pragma unroll
    for (int n = 0; n < 4; ++n) acc[m][n] = zf;
  const int tid = threadIdx.x, l = tid & 63, lr = l & 15, lk = l >> 4;
  const int w = tid >> 6, wr = w >> 1, wc = w & 1;
  const int arow = tid >> 2, ako = (tid & 3) << 3;
  auto stage = [&](int kt, int buf) {  // 3 VMEM loads per thread
    GLOAD16(ctx + (size_t)(bm0 + arow) * 1024 + kt * 32 + ako,
            ldsA + buf * 2048 + tid * 8);
#pragma unroll
    for (int i = 0; i < 2; ++i) {
      int c = i * 256 + tid;
      int row = c >> 2, ko = (c & 3) << 3;
      GLOAD16(wo + (size_t)(bn0 + row) * 1024 + kt * 32 + ko,
              ldsB + buf * 4096 + c * 8);
    }
  };
  stage(0, 0);
  stage(1, 1);
  int cur = 0, nx2 = 2;
  for (int kt = 0; kt < 32; ++kt) {
    if (kt < 31) asm volatile("s_waitcnt vmcnt(3)" ::: "memory");
    else         asm volatile("s_waitcnt vmcnt(0)" ::: "memory");
    __builtin_amdgcn_s_barrier();
    __builtin_amdgcn_sched_barrier(0);
    if (kt + 2 < 32) stage(kt + 2, nx2);
    const u16* lA = ldsA + cur * 2048;
    const u16* lB = ldsB + cur * 4096;
    bf16x8 af[2], bfr[4];
#pragma unroll
    for (int m = 0; m < 2; ++m)
      af[m] = *(const bf16x8*)(lA + (wr * 32 + m * 16 + lr) * 32 + lk * 8);
#pragma unroll
    for (int n = 0; n < 4; ++n)
      bfr[n] = *(const bf16x8*)(lB + (wc * 64 + n * 16 + lr) * 32 + lk * 8);
#pragma unroll
    for (int m = 0; m < 2; ++m)
#pragma unroll
      for (int n = 0; n < 4; ++n)
        acc[m][n] = __builtin_amdgcn_mfma_f32_16x16x32_bf16(bfr[n], af[m], acc[m][n], 0, 0, 0);
    cur = (cur == 2) ? 0 : cur + 1;
    nx2 = (nx2 == 2) ? 0 : nx2 + 1;
  }
#pragma unroll
  for (int n = 0; n < 4; ++n) {
    f32x4 bv4 = *(const f32x4*)&bo[bn0 + wc * 64 + n * 16 + lk * 4];
#pragma unroll
    for (int m = 0; m < 2; ++m) {
      int row = bm0 + wr * 32 + m * 16 + lr;
      int col = bn0 + wc * 64 + n * 16 + lk * 4;
      f32x4 ov = acc[m][n] + bv4;
      *(f32x4*)(out + (size_t)row * 1024 + col) = ov;
    }
  }
}

// --------------------------------------------- RMSNorm + RoPE -> fragment layouts
// K path stores key s at hw-row swapbits2,3(s&31): QK's score registers land
// exactly in PV's B-fragment order (no cross-lane exchange in attn).
__global__ __launch_bounds__(256) void rmsrope(const u16* __restrict__ Qb,
    const u16* __restrict__ Kb, const float* __restrict__ gq, const float* __restrict__ gk,
    const float* __restrict__ fc, const float* __restrict__ fs,
    u16* __restrict__ Qf, u16* __restrict__ Kf) {
  const int row = blockIdx.x;
  const int which = blockIdx.y;
  const u16* src = (which ? Kb : Qb) + (size_t)row * 1024;
  const float* g = which ? gk : gq;
  const int t = threadIdx.x;
  u16x4 raw = *(const u16x4*)(src + t * 4);
  float v0 = bf2f(raw[0]), v1 = bf2f(raw[1]), v2 = bf2f(raw[2]), v3 = bf2f(raw[3]);
  float ss = v0 * v0 + v1 * v1 + v2 * v2 + v3 * v3;
#pragma unroll
  for (int mm = 1; mm < 64; mm <<= 1) ss += __shfl_xor(ss, mm);
  __shared__ float red[4];
  if ((t & 63) == 0) red[t >> 6] = ss;
  __syncthreads();
  float rstd = rsqrtf((red[0] + red[1] + red[2] + red[3]) * (1.0f / 1024.0f) + 1e-6f);
  if (!which) rstd *= 0.18033688011112042f;   // 0.125 * log2(e) folded into q
  int d = t * 4, hh = d >> 6, dh = d & 63, p = dh >> 1;
  int s = row & 2047, b = row >> 11;
  float c0 = fc[(s << 5) + p], s0 = fs[(s << 5) + p];
  float c1 = fc[(s << 5) + p + 1], s1 = fs[(s << 5) + p + 1];
  float x0 = v0 * rstd * g[d];
  float x1 = v1 * rstd * g[d + 1];
  float x2 = v2 * rstd * g[d + 2];
  float x3 = v3 * rstd * g[d + 3];
  u16x4 o;
  o[0] = f2bf(x0 * c0 - x1 * s0);
  o[1] = f2bf(x0 * s0 + x1 * c0);
  o[2] = f2bf(x2 * c1 - x3 * s1);
  o[3] = f2bf(x2 * s1 + x3 * c1);
  const size_t base = (size_t)(b * 16 + hh) * 131072;
  const int hs = dh >> 4, hi = (dh >> 3) & 1, j0 = dh & 7;
  size_t addr;
  if (!which) {
    addr = base + (size_t)((s >> 5) * 4 + hs) * 512 + ((hi << 5) + (s & 31)) * 8 + j0;
  } else {
    int srow = s & 31;                         // permute: swap bits 2 and 3
    int swp = ((srow >> 2) ^ (srow >> 3)) & 1;
    srow ^= (swp << 2) | (swp << 3);
    addr = base + (size_t)(((s >> 6) * 4 + hs) * 2 + ((s >> 5) & 1)) * 512 +
           ((hi << 5) + srow) * 8 + j0;
  }
  *(u16x4*)((which ? Kf : Qf) + addr) = o;
}

// --------------------------------------------- flash attention (non-causal)
// 512 blocks x 256 thr (4 waves). R23 = R22 + split PV accumulator chains:
// O0a/O0b, O1a/O1b (ks{0,2} vs ks{1,3}), merged once at the end -- dependent
// PV MFMA chain depth 4 -> 2. Isolated change (R18 bundled this with V-dbuf
// and regressed); VGPR ~92+32=124, grid 512 = 2 blocks/CU budget 256 -- safe.
__global__ __launch_bounds__(256) void attn_kernel(const u16* __restrict__ Qf,
    const u16* __restrict__ Kf, const u16* __restrict__ Vf, u16* __restrict__ ctx) {
  __shared__ u16 KVbuf[4][8192];   // 4 x (K 8KB | V 8KB)
  const int tid = threadIdx.x;
  const int w = tid >> 6, l = tid & 63;
  const int lq = l & 31, hi = l >> 5;
  const int id = blockIdx.x;
  const int qt = (id >> 3) & 15;
  const int hb = (id & 7) | ((id >> 7) << 3);
  const int h = hb & 15, b = hb >> 4;
  const int bh = b * 16 + h;
  const u16* Qp = Qf + (size_t)bh * 131072;
  const u16* Kp = Kf + (size_t)bh * 131072;
  const u16* Vp = Vf + (size_t)bh * 131072;
  bf16x8 qf[4];
#pragma unroll
  for (int hs = 0; hs < 4; ++hs)
    qf[hs] = *(const bf16x8*)(Qp + (size_t)((qt * 4 + w) * 4 + hs) * 512 + l * 8);

  auto stageKV = [&](int t, u16* dst) {  // 4 gload_lds per thread (16KB/block)
    GLOAD16(Kp + (size_t)t * 4096 + tid * 8, dst + tid * 8);
    GLOAD16(Kp + (size_t)t * 4096 + 2048 + tid * 8, dst + 2048 + tid * 8);
    GLOAD16(Vp + (size_t)t * 4096 + tid * 8, dst + 4096 + tid * 8);
    GLOAD16(Vp + (size_t)t * 4096 + 2048 + tid * 8, dst + 6144 + tid * 8);
  };

  const f32x16 z16 = {0,0,0,0, 0,0,0,0, 0,0,0,0, 0,0,0,0};
  f32x16 O0a = z16, O0b = z16, O1a = z16, O1b = z16;
  float lsum = 0.f;

  auto qk_lds = [&](const u16* Kb_, f32x16& s0, f32x16& s1) {
    s0 = z16; s1 = z16;
    __builtin_amdgcn_s_setprio(1);
#pragma unroll
    for (int hs = 0; hs < 4; ++hs) {
      bf16x8 k0 = *(const bf16x8*)(Kb_ + (hs * 2 + 0) * 512 + l * 8);
      bf16x8 k1 = *(const bf16x8*)(Kb_ + (hs * 2 + 1) * 512 + l * 8);
      s0 = __builtin_amdgcn_mfma_f32_32x32x16_bf16(k0, qf[hs], s0, 0, 0, 0);
      s1 = __builtin_amdgcn_mfma_f32_32x32x16_bf16(k1, qf[hs], s1, 0, 0, 0);
    }
    __builtin_amdgcn_s_setprio(0);
  };

  auto sm_pv = [&](const u16* Vb_, f32x16& sc0, f32x16& sc1) {
    u32 pk0[8], pk1[8];
    float tm[8];
#pragma unroll
    for (int m = 0; m < 8; ++m) {
      float a0 = __builtin_amdgcn_exp2f(sc0[2 * m]);
      float a1 = __builtin_amdgcn_exp2f(sc0[2 * m + 1]);
      float c0 = __builtin_amdgcn_exp2f(sc1[2 * m]);
      float c1 = __builtin_amdgcn_exp2f(sc1[2 * m + 1]);
      tm[m] = (a0 + a1) + (c0 + c1);
      bf16x2 pA; pA[0] = (__bf16)a0; pA[1] = (__bf16)a1;
      bf16x2 pC; pC[0] = (__bf16)c0; pC[1] = (__bf16)c1;
      pk0[m] = __builtin_bit_cast(u32, pA);
      pk1[m] = __builtin_bit_cast(u32, pC);
    }
    float rs = ((tm[0] + tm[1]) + (tm[2] + tm[3])) +
               ((tm[4] + tm[5]) + (tm[6] + tm[7]));   // tree, short dep chain
    rs += __shfl_xor(rs, 32);
    lsum += rs;
    // exchange-free P (R22): K pre-permutation makes pb[ks] = packed sc regs.
    bf16x8 pb[4];
    {
      u32x4 pw0 = {pk0[0], pk0[1], pk0[2], pk0[3]};
      pb[0] = __builtin_bit_cast(bf16x8, pw0);
      u32x4 pw1 = {pk0[4], pk0[5], pk0[6], pk0[7]};
      pb[1] = __builtin_bit_cast(bf16x8, pw1);
      u32x4 pw2 = {pk1[0], pk1[1], pk1[2], pk1[3]};
      pb[2] = __builtin_bit_cast(bf16x8, pw2);
      u32x4 pw3 = {pk1[4], pk1[5], pk1[6], pk1[7]};
      pb[3] = __builtin_bit_cast(bf16x8, pw3);
    }
    __builtin_amdgcn_s_setprio(1);
    {   // split chains: each accumulator sees 2 dependent MFMAs per sub-iter
      bf16x8 v0 = *(const bf16x8*)(Vb_ + 0 * 512 + l * 8);
      bf16x8 v1 = *(const bf16x8*)(Vb_ + 1 * 512 + l * 8);
      bf16x8 v2 = *(const bf16x8*)(Vb_ + 2 * 512 + l * 8);
      bf16x8 v3 = *(const bf16x8*)(Vb_ + 3 * 512 + l * 8);
      bf16x8 v4 = *(const bf16x8*)(Vb_ + 4 * 512 + l * 8);
      bf16x8 v5 = *(const bf16x8*)(Vb_ + 5 * 512 + l * 8);
      bf16x8 v6 = *(const bf16x8*)(Vb_ + 6 * 512 + l * 8);
      bf16x8 v7 = *(const bf16x8*)(Vb_ + 7 * 512 + l * 8);
      O0a = __builtin_amdgcn_mfma_f32_32x32x16_bf16(v0, pb[0], O0a, 0, 0, 0);
      O1a = __builtin_amdgcn_mfma_f32_32x32x16_bf16(v1, pb[0], O1a, 0, 0, 0);
      O0b = __builtin_amdgcn_mfma_f32_32x32x16_bf16(v2, pb[1], O0b, 0, 0, 0);
      O1b = __builtin_amdgcn_mfma_f32_32x32x16_bf16(v3, pb[1], O1b, 0, 0, 0);
      O0a = __builtin_amdgcn_mfma_f32_32x32x16_bf16(v4, pb[2], O0a, 0, 0, 0);
      O1a = __builtin_amdgcn_mfma_f32_32x32x16_bf16(v5, pb[2], O1a, 0, 0, 0);
      O0b = __builtin_amdgcn_mfma_f32_32x32x16_bf16(v6, pb[3], O0b, 0, 0, 0);
      O1b = __builtin_amdgcn_mfma_f32_32x32x16_bf16(v7, pb[3], O1b, 0, 0, 0);
    }
    __builtin_amdgcn_s_setprio(0);
  };

  f32x16 scA0, scA1, scB0, scB1;
  u16* pA = &KVbuf[0][0];
  u16* pB = &KVbuf[1][0];
  u16* pC = &KVbuf[2][0];
  u16* pD = &KVbuf[3][0];
  // prologue: stage tiles 0..2 (qf loads are oldest in the VMEM queue)
  stageKV(0, pA);
  stageKV(1, pB);
  stageKV(2, pC);
  asm volatile("s_waitcnt vmcnt(4)" ::: "memory");   // qf,KV0,KV1 landed; KV2 fly
  __builtin_amdgcn_s_barrier();
  __builtin_amdgcn_sched_barrier(0);
  qk_lds(pA, scA0, scA1);                            // scores for tile 0
#pragma unroll 1
  for (int dt = 0; dt < 16; ++dt) {
    const int t = dt * 2;
    {   // sub-iter t: scores(t) in scA; QK(t+1) -> scB; sm_pv(t) from pA's V
      if (t < 30) asm volatile("s_waitcnt vmcnt(4)" ::: "memory");
      else        asm volatile("s_waitcnt vmcnt(0)" ::: "memory");
      __builtin_amdgcn_s_barrier();
      __builtin_amdgcn_sched_barrier(0);
      if (t + 3 < 32) stageKV(t + 3, pD);  // pD: last read at sub-iter t-1
      qk_lds(pB, scB0, scB1);              // tile t+1 landed per vmcnt above
      sm_pv(pA + 4096, scA0, scA1);
    }
    {   // sub-iter t+1: scores in scB; QK(t+2) -> scA; sm_pv(t+1) from pB's V
      if (t + 1 < 30) asm volatile("s_waitcnt vmcnt(4)" ::: "memory");
      else            asm volatile("s_waitcnt vmcnt(0)" ::: "memory");
      __builtin_amdgcn_s_barrier();
      __builtin_amdgcn_sched_barrier(0);
      if (t + 4 < 32) stageKV(t + 4, pA);  // pA: last read this even sub-iter
      if (t + 2 < 32) qk_lds(pC, scA0, scA1);
      sm_pv(pB + 4096, scB0, scB1);
    }
    u16* t1 = pA; pA = pC; pC = t1;        // rotate ring by 2
    u16* t2 = pB; pB = pD; pD = t2;
  }
  f32x16 O0 = O0a + O0b, O1 = O1a + O1b;
  float inv = 1.0f / lsum;
  const int q0 = qt * 128 + w * 32;
  const size_t rowoff = ((size_t)(b * 2048 + q0 + lq)) * 1024 + h * 64;
#pragma unroll
  for (int g = 0; g < 4; ++g) {                 // hd = 8g + 4hi + rr (+32 for O1)
    u16x4 oa, ob;
#pragma unroll
    for (int rr = 0; rr < 4; ++rr) {
      oa[rr] = f2bf(O0[4 * g + rr] * inv);
      ob[rr] = f2bf(O1[4 * g + rr] * inv);
    }
    *(u16x4*)(ctx + rowoff + 8 * g + 4 * hi) = oa;
    *(u16x4*)(ctx + rowoff + 32 + 8 * g + 4 * hi) = ob;
  }
}

// ---------------------------------------------------------------- launch
extern "C" void kernel_launch(void* const* d_in, const int* in_sizes, int n_in,
                              void* d_out, int out_size, void* d_ws, size_t ws_size,
                              hipStream_t stream) {
  (void)in_sizes; (void)n_in; (void)out_size; (void)ws_size;
  const float* x  = (const float*)d_in[0];
  const float* Wq = (const float*)d_in[1];
  const float* bq = (const float*)d_in[2];
  const float* Wk = (const float*)d_in[3];
  const float* bk = (const float*)d_in[4];
  const float* Wv = (const float*)d_in[5];
  const float* bv = (const float*)d_in[6];
  const float* Wo = (const float*)d_in[7];
  const float* bo = (const float*)d_in[8];
  const float* gq = (const float*)d_in[9];
  const float* gk = (const float*)d_in[10];
  const float* fc = (const float*)d_in[11];
  const float* fs = (const float*)d_in[12];
  float* out = (float*)d_out;
  char* ws = (char*)d_ws;
  u16*  xb  = (u16*)(ws + 0);           //  8 MB  x bf16 [4096][1024]
  u16*  wqb = (u16*)(ws + 8388608);     //  2 MB each, contiguous x4
  u16*  wkb = (u16*)(ws + 10485760);
  u16*  wvb = (u16*)(ws + 12582912);
  u16*  wob = (u16*)(ws + 14680064);
  u16*  Qfb = (u16*)(ws + 16777216);    //  8 MB bf16 pre-norm q rows
  u16*  Kfb = (u16*)(ws + 25165824);    //  8 MB pre-norm k rows
  u16*  Qfr = (u16*)(ws + 33554432);    //  8 MB Q fragment-major
  u16*  Kfr = (u16*)(ws + 41943040);    //  8 MB K fragment-major (row-permuted)
  u16*  Vfr = (u16*)(ws + 50331648);    //  8 MB V fragment-major
  u16*  ctx = (u16*)(ws + 58720256);    //  8 MB bf16 [B,S,D]

  f2ball_kernel<<<8192, 256, 0, stream>>>(x, Wq, Wk, Wv, Wo, xb, wqb);
  qkv_gemm<<<dim3(32, 8, 3), 256, 0, stream>>>(xb, wqb, wkb, wvb, bq, bk, bv, Qfb, Kfb, Vfr);
  rmsrope<<<dim3(4096, 2), 256, 0, stream>>>(Qfb, Kfb, gq, gk, fc, fs, Qfr, Kfr);
  attn_kernel<<<512, 256, 0, stream>>>(Qfr, Kfr, Vfr, ctx);
  proj_gemm<<<dim3(64, 8), 256, 0, stream>>>(ctx, wob, bo, out);
}

// Round 24
// 129.324 us; speedup vs baseline: 1.0053x; 1.0053x over previous
//
#include <hip/hip_runtime.h>

typedef unsigned short u16;
typedef unsigned int u32;
typedef u16 u16x4 __attribute__((ext_vector_type(4)));
typedef u16 u16x8 __attribute__((ext_vector_type(8)));
typedef u32 u32x4 __attribute__((ext_vector_type(4)));
typedef float f32x4 __attribute__((ext_vector_type(4)));
typedef float f32x16 __attribute__((ext_vector_type(16)));
typedef __bf16 bf16x2 __attribute__((ext_vector_type(2)));
typedef __bf16 bf16x8 __attribute__((ext_vector_type(8)));

#define GLOAD16(gp, lp)                                             \
  __builtin_amdgcn_global_load_lds(                                 \
      (const __attribute__((address_space(1))) void*)(gp),          \
      (__attribute__((address_space(3))) void*)(lp), 16, 0, 0)

__device__ __forceinline__ u16 f2bf(float f) {
  unsigned int u = __builtin_bit_cast(unsigned int, f);
  u += 0x7FFFu + ((u >> 16) & 1u);
  return (u16)(u >> 16);
}
__device__ __forceinline__ float bf2f(u16 h) {
  return __builtin_bit_cast(float, (u32)h << 16);
}

// ------------------------------------------- all f32->bf16 converts, 1 launch
__global__ __launch_bounds__(256) void f2ball_kernel(const float* __restrict__ x,
    const float* __restrict__ w0, const float* __restrict__ w1,
    const float* __restrict__ w2, const float* __restrict__ w3,
    u16* __restrict__ xb, u16* __restrict__ wb) {
  int g = blockIdx.x * 256 + threadIdx.x;
  const float* s;
  u16* d;
  size_t off;
  if (g < 1048576) {
    s = x; d = xb; off = (size_t)g * 4;
  } else {
    int wi = g - 1048576;
    int sel = wi >> 18;
    int r = wi & 262143;
    s = (sel == 0) ? w0 : ((sel == 1) ? w1 : ((sel == 2) ? w2 : w3));
    d = wb + (size_t)sel * 1048576;
    off = (size_t)r * 4;
  }
  f32x4 v = *(const f32x4*)(s + off);
  u16x4 o;
  o[0] = f2bf(v[0]); o[1] = f2bf(v[1]); o[2] = f2bf(v[2]); o[3] = f2bf(v[3]);
  *(u16x4*)(d + off) = o;
}

// --------------------------------------------- NT GEMM core: C = A * W^T
// 128x128 tile, BK=32, 256 thr (4 waves). 3-buffer counted-vmcnt pipeline.
// SWAP=false: acc[m][n][r] = C[row=bm0+wr*64+m*16+lk*4+r][col=bn0+wc*64+n*16+lr]
// SWAP=true : acc[m][n][r] = C[row=bm0+wr*64+m*16+lr][col=bn0+wc*64+n*16+lk*4+r]
template <bool SWAP>
__device__ __forceinline__ void gemm_core(const u16* __restrict__ A,
                                          const u16* __restrict__ W,
                                          int bm0, int bn0,
                                          u16* ldsA, u16* ldsB,
                                          f32x4 acc[4][4]) {
  const int tid = threadIdx.x;
  const int l = tid & 63;
  const int lr = l & 15, lk = l >> 4;
  const int w = tid >> 6;
  const int wr = w >> 1, wc = w & 1;
  const int srow = tid >> 2, sko = (tid & 3) << 3;
  auto stage = [&](int kt, int buf) {  // 4 VMEM loads per thread
#pragma unroll
    for (int it = 0; it < 2; ++it) {
      int row = it * 64 + srow;
      GLOAD16(A + (size_t)(bm0 + row) * 1024 + kt * 32 + sko,
              ldsA + buf * 4096 + (it * 256 + tid) * 8);
      GLOAD16(W + (size_t)(bn0 + row) * 1024 + kt * 32 + sko,
              ldsB + buf * 4096 + (it * 256 + tid) * 8);
    }
  };
  stage(0, 0);
  stage(1, 1);
  int cur = 0, nx2 = 2;
  for (int kt = 0; kt < 32; ++kt) {
    if (kt < 31) asm volatile("s_waitcnt vmcnt(4)" ::: "memory");
    else         asm volatile("s_waitcnt vmcnt(0)" ::: "memory");
    __builtin_amdgcn_s_barrier();
    __builtin_amdgcn_sched_barrier(0);
    if (kt + 2 < 32) stage(kt + 2, nx2);
    const u16* lA = ldsA + cur * 4096;
    const u16* lB = ldsB + cur * 4096;
    bf16x8 af[4], bfr[4];
#pragma unroll
    for (int m = 0; m < 4; ++m)
      af[m] = *(const bf16x8*)(lA + (wr * 64 + m * 16 + lr) * 32 + lk * 8);
#pragma unroll
    for (int n = 0; n < 4; ++n)
      bfr[n] = *(const bf16x8*)(lB + (wc * 64 + n * 16 + lr) * 32 + lk * 8);
#pragma unroll
    for (int m = 0; m < 4; ++m)
#pragma unroll
      for (int n = 0; n < 4; ++n) {
        if (SWAP)
          acc[m][n] = __builtin_amdgcn_mfma_f32_16x16x32_bf16(bfr[n], af[m], acc[m][n], 0, 0, 0);
        else
          acc[m][n] = __builtin_amdgcn_mfma_f32_16x16x32_bf16(af[m], bfr[n], acc[m][n], 0, 0, 0);
      }
    cur = (cur == 2) ? 0 : cur + 1;
    nx2 = (nx2 == 2) ? 0 : nx2 + 1;
  }
}

// --------------------------------------------- fused QKV projection
// z=0: Q -> Qb rows (swapped core, u16x4 stores); z=1: K likewise;
// z=2: V -> V-frag (unswapped core, original epilogue).
__global__ __launch_bounds__(256) void qkv_gemm(const u16* __restrict__ xb,
    const u16* __restrict__ wq, const u16* __restrict__ wk, const u16* __restrict__ wv,
    const float* __restrict__ bq, const float* __restrict__ bk, const float* __restrict__ bv,
    u16* __restrict__ Qb, u16* __restrict__ Kb, u16* __restrict__ Vf) {
  __shared__ u16 ldsA[3 * 4096];
  __shared__ u16 ldsB[3 * 4096];
  const int z = blockIdx.z;
  const u16* W = (z == 0) ? wq : ((z == 1) ? wk : wv);
  const float* bias = (z == 0) ? bq : ((z == 1) ? bk : bv);
  const int bm0 = blockIdx.x * 128, bn0 = blockIdx.y * 128;
  const f32x4 zf = {0.f, 0.f, 0.f, 0.f};
  f32x4 acc[4][4];
#pragma unroll
  for (int m = 0; m < 4; ++m)
#pragma unroll
    for (int n = 0; n < 4; ++n) acc[m][n] = zf;
  const int tid = threadIdx.x, l = tid & 63, lr = l & 15, lk = l >> 4;
  const int w = tid >> 6, wr = w >> 1, wc = w & 1;
  if (z < 2) {
    gemm_core<true>(xb, W, bm0, bn0, ldsA, ldsB, acc);
    u16* outp = z ? Kb : Qb;
#pragma unroll
    for (int n = 0; n < 4; ++n) {
      f32x4 bv4 = *(const f32x4*)&bias[bn0 + wc * 64 + n * 16 + lk * 4];
#pragma unroll
      for (int m = 0; m < 4; ++m) {
        int row = bm0 + wr * 64 + m * 16 + lr;
        int col = bn0 + wc * 64 + n * 16 + lk * 4;
        u16x4 o;
#pragma unroll
        for (int r = 0; r < 4; ++r) o[r] = f2bf(acc[m][n][r] + bv4[r]);
        *(u16x4*)(outp + (size_t)row * 1024 + col) = o;
      }
    }
  } else {
    gemm_core<false>(xb, W, bm0, bn0, ldsA, ldsB, acc);
    float bcol[4];
#pragma unroll
    for (int n = 0; n < 4; ++n) bcol[n] = bias[bn0 + wc * 64 + n * 16 + lr];
#pragma unroll
    for (int m = 0; m < 4; ++m)
#pragma unroll
      for (int n = 0; n < 4; ++n) {
        int row = bm0 + wr * 64 + m * 16 + lk * 4;   // key base (r = 0..3)
        int col = bn0 + wc * 64 + n * 16 + lr;
        int b = row >> 11, sf = row & 2047, hh = col >> 6, hd = col & 63;
        int t = sf >> 6, kin = sf & 63;
        int ks = kin >> 4, hiv = (kin >> 3) & 1, j0 = kin & 7;
        int vhalf = hd >> 5, lq = hd & 31;
        u16x4 o;
#pragma unroll
        for (int r = 0; r < 4; ++r) o[r] = f2bf(acc[m][n][r] + bcol[n]);
        size_t addr = (size_t)(b * 16 + hh) * 131072 +
                      (size_t)(((t * 4 + ks) * 2 + vhalf)) * 512 +
                      ((hiv << 5) + lq) * 8 + j0;
        *(u16x4*)(Vf + addr) = o;
      }
  }
}

// --------------------------------------------- output projection, 64x128 tile
__global__ __launch_bounds__(256) void proj_gemm(const u16* __restrict__ ctx,
    const u16* __restrict__ wo, const float* __restrict__ bo, float* __restrict__ out) {
  __shared__ u16 ldsA[3 * 2048];
  __shared__ u16 ldsB[3 * 4096];
  const int bm0 = blockIdx.x * 64, bn0 = blockIdx.y * 128;
  const f32x4 zf = {0.f, 0.f, 0.f, 0.f};
  f32x4 acc[2][4];
#pragma unroll
  for (int m = 0; m < 2; ++m)
#pragma unroll
    for (int n = 0; n < 4; ++n) acc[m][n] = zf;
  const int tid = threadIdx.x, l = tid & 63, lr = l & 15, lk = l >> 4;
  const int w = tid >> 6, wr = w >> 1, wc = w & 1;
  const int arow = tid >> 2, ako = (tid & 3) << 3;
  auto stage = [&](int kt, int buf) {  // 3 VMEM loads per thread
    GLOAD16(ctx + (size_t)(bm0 + arow) * 1024 + kt * 32 + ako,
            ldsA + buf * 2048 + tid * 8);
#pragma unroll
    for (int i = 0; i < 2; ++i) {
      int c = i * 256 + tid;
      int row = c >> 2, ko = (c & 3) << 3;
      GLOAD16(wo + (size_t)(bn0 + row) * 1024 + kt * 32 + ko,
              ldsB + buf * 4096 + c * 8);
    }
  };
  stage(0, 0);
  stage(1, 1);
  int cur = 0, nx2 = 2;
  for (int kt = 0; kt < 32; ++kt) {
    if (kt < 31) asm volatile("s_waitcnt vmcnt(3)" ::: "memory");
    else         asm volatile("s_waitcnt vmcnt(0)" ::: "memory");
    __builtin_amdgcn_s_barrier();
    __builtin_amdgcn_sched_barrier(0);
    if (kt + 2 < 32) stage(kt + 2, nx2);
    const u16* lA = ldsA + cur * 2048;
    const u16* lB = ldsB + cur * 4096;
    bf16x8 af[2], bfr[4];
#pragma unroll
    for (int m = 0; m < 2; ++m)
      af[m] = *(const bf16x8*)(lA + (wr * 32 + m * 16 + lr) * 32 + lk * 8);
#pragma unroll
    for (int n = 0; n < 4; ++n)
      bfr[n] = *(const bf16x8*)(lB + (wc * 64 + n * 16 + lr) * 32 + lk * 8);
#pragma unroll
    for (int m = 0; m < 2; ++m)
#pragma unroll
      for (int n = 0; n < 4; ++n)
        acc[m][n] = __builtin_amdgcn_mfma_f32_16x16x32_bf16(bfr[n], af[m], acc[m][n], 0, 0, 0);
    cur = (cur == 2) ? 0 : cur + 1;
    nx2 = (nx2 == 2) ? 0 : nx2 + 1;
  }
#pragma unroll
  for (int n = 0; n < 4; ++n) {
    f32x4 bv4 = *(const f32x4*)&bo[bn0 + wc * 64 + n * 16 + lk * 4];
#pragma unroll
    for (int m = 0; m < 2; ++m) {
      int row = bm0 + wr * 32 + m * 16 + lr;
      int col = bn0 + wc * 64 + n * 16 + lk * 4;
      f32x4 ov = acc[m][n] + bv4;
      *(f32x4*)(out + (size_t)row * 1024 + col) = ov;
    }
  }
}

// --------------------------------------------- RMSNorm + RoPE -> fragment layouts
// K path stores key s at hw-row swapbits2,3(s&31): QK's score registers land
// exactly in PV's B-fragment order (no cross-lane exchange in attn).
__global__ __launch_bounds__(256) void rmsrope(const u16* __restrict__ Qb,
    const u16* __restrict__ Kb, const float* __restrict__ gq, const float* __restrict__ gk,
    const float* __restrict__ fc, const float* __restrict__ fs,
    u16* __restrict__ Qf, u16* __restrict__ Kf) {
  const int row = blockIdx.x;
  const int which = blockIdx.y;
  const u16* src = (which ? Kb : Qb) + (size_t)row * 1024;
  const float* g = which ? gk : gq;
  const int t = threadIdx.x;
  u16x4 raw = *(const u16x4*)(src + t * 4);
  float v0 = bf2f(raw[0]), v1 = bf2f(raw[1]), v2 = bf2f(raw[2]), v3 = bf2f(raw[3]);
  float ss = v0 * v0 + v1 * v1 + v2 * v2 + v3 * v3;
#pragma unroll
  for (int mm = 1; mm < 64; mm <<= 1) ss += __shfl_xor(ss, mm);
  __shared__ float red[4];
  if ((t & 63) == 0) red[t >> 6] = ss;
  __syncthreads();
  float rstd = rsqrtf((red[0] + red[1] + red[2] + red[3]) * (1.0f / 1024.0f) + 1e-6f);
  if (!which) rstd *= 0.18033688011112042f;   // 0.125 * log2(e) folded into q
  int d = t * 4, hh = d >> 6, dh = d & 63, p = dh >> 1;
  int s = row & 2047, b = row >> 11;
  float c0 = fc[(s << 5) + p], s0 = fs[(s << 5) + p];
  float c1 = fc[(s << 5) + p + 1], s1 = fs[(s << 5) + p + 1];
  float x0 = v0 * rstd * g[d];
  float x1 = v1 * rstd * g[d + 1];
  float x2 = v2 * rstd * g[d + 2];
  float x3 = v3 * rstd * g[d + 3];
  u16x4 o;
  o[0] = f2bf(x0 * c0 - x1 * s0);
  o[1] = f2bf(x0 * s0 + x1 * c0);
  o[2] = f2bf(x2 * c1 - x3 * s1);
  o[3] = f2bf(x2 * s1 + x3 * c1);
  const size_t base = (size_t)(b * 16 + hh) * 131072;
  const int hs = dh >> 4, hi = (dh >> 3) & 1, j0 = dh & 7;
  size_t addr;
  if (!which) {
    addr = base + (size_t)((s >> 5) * 4 + hs) * 512 + ((hi << 5) + (s & 31)) * 8 + j0;
  } else {
    int srow = s & 31;                         // permute: swap bits 2 and 3
    int swp = ((srow >> 2) ^ (srow >> 3)) & 1;
    srow ^= (swp << 2) | (swp << 3);
    addr = base + (size_t)(((s >> 6) * 4 + hs) * 2 + ((s >> 5) & 1)) * 512 +
           ((hi << 5) + srow) * 8 + j0;
  }
  *(u16x4*)((which ? Kf : Qf) + addr) = o;
}

// --------------------------------------------- flash attention (non-causal)
// 512 blocks x 256 thr (4 waves). R22 configuration (best measured: 51.5 us):
// LDS-KV 4-buffer ring + cross-iteration ILP (QK(t+1) before sm_pv(t)) +
// exchange-free P via K-row pre-permutation + max-free exp2-domain softmax.
// (R23's split-accumulator A/B was null -> reverted; VGPR back to ~92.)
__global__ __launch_bounds__(256) void attn_kernel(const u16* __restrict__ Qf,
    const u16* __restrict__ Kf, const u16* __restrict__ Vf, u16* __restrict__ ctx) {
  __shared__ u16 KVbuf[4][8192];   // 4 x (K 8KB | V 8KB)
  const int tid = threadIdx.x;
  const int w = tid >> 6, l = tid & 63;
  const int lq = l & 31, hi = l >> 5;
  const int id = blockIdx.x;
  const int qt = (id >> 3) & 15;
  const int hb = (id & 7) | ((id >> 7) << 3);
  const int h = hb & 15, b = hb >> 4;
  const int bh = b * 16 + h;
  const u16* Qp = Qf + (size_t)bh * 131072;
  const u16* Kp = Kf + (size_t)bh * 131072;
  const u16* Vp = Vf + (size_t)bh * 131072;
  bf16x8 qf[4];
#pragma unroll
  for (int hs = 0; hs < 4; ++hs)
    qf[hs] = *(const bf16x8*)(Qp + (size_t)((qt * 4 + w) * 4 + hs) * 512 + l * 8);

  auto stageKV = [&](int t, u16* dst) {  // 4 gload_lds per thread (16KB/block)
    GLOAD16(Kp + (size_t)t * 4096 + tid * 8, dst + tid * 8);
    GLOAD16(Kp + (size_t)t * 4096 + 2048 + tid * 8, dst + 2048 + tid * 8);
    GLOAD16(Vp + (size_t)t * 4096 + tid * 8, dst + 4096 + tid * 8);
    GLOAD16(Vp + (size_t)t * 4096 + 2048 + tid * 8, dst + 6144 + tid * 8);
  };

  const f32x16 z16 = {0,0,0,0, 0,0,0,0, 0,0,0,0, 0,0,0,0};
  f32x16 O0 = z16, O1 = z16;
  float lsum = 0.f;

  auto qk_lds = [&](const u16* Kb_, f32x16& s0, f32x16& s1) {
    s0 = z16; s1 = z16;
    __builtin_amdgcn_s_setprio(1);
#pragma unroll
    for (int hs = 0; hs < 4; ++hs) {
      bf16x8 k0 = *(const bf16x8*)(Kb_ + (hs * 2 + 0) * 512 + l * 8);
      bf16x8 k1 = *(const bf16x8*)(Kb_ + (hs * 2 + 1) * 512 + l * 8);
      s0 = __builtin_amdgcn_mfma_f32_32x32x16_bf16(k0, qf[hs], s0, 0, 0, 0);
      s1 = __builtin_amdgcn_mfma_f32_32x32x16_bf16(k1, qf[hs], s1, 0, 0, 0);
    }
    __builtin_amdgcn_s_setprio(0);
  };

  auto sm_pv = [&](const u16* Vb_, f32x16& sc0, f32x16& sc1) {
    u32 pk0[8], pk1[8];
    float tm[8];
#pragma unroll
    for (int m = 0; m < 8; ++m) {
      float a0 = __builtin_amdgcn_exp2f(sc0[2 * m]);
      float a1 = __builtin_amdgcn_exp2f(sc0[2 * m + 1]);
      float c0 = __builtin_amdgcn_exp2f(sc1[2 * m]);
      float c1 = __builtin_amdgcn_exp2f(sc1[2 * m + 1]);
      tm[m] = (a0 + a1) + (c0 + c1);
      bf16x2 pA; pA[0] = (__bf16)a0; pA[1] = (__bf16)a1;
      bf16x2 pC; pC[0] = (__bf16)c0; pC[1] = (__bf16)c1;
      pk0[m] = __builtin_bit_cast(u32, pA);
      pk1[m] = __builtin_bit_cast(u32, pC);
    }
    float rs = ((tm[0] + tm[1]) + (tm[2] + tm[3])) +
               ((tm[4] + tm[5]) + (tm[6] + tm[7]));   // tree, short dep chain
    rs += __shfl_xor(rs, 32);
    lsum += rs;
    // exchange-free P (R22): K pre-permutation makes pb[ks] = packed sc regs.
    bf16x8 pb[4];
    {
      u32x4 pw0 = {pk0[0], pk0[1], pk0[2], pk0[3]};
      pb[0] = __builtin_bit_cast(bf16x8, pw0);
      u32x4 pw1 = {pk0[4], pk0[5], pk0[6], pk0[7]};
      pb[1] = __builtin_bit_cast(bf16x8, pw1);
      u32x4 pw2 = {pk1[0], pk1[1], pk1[2], pk1[3]};
      pb[2] = __builtin_bit_cast(bf16x8, pw2);
      u32x4 pw3 = {pk1[4], pk1[5], pk1[6], pk1[7]};
      pb[3] = __builtin_bit_cast(bf16x8, pw3);
    }
    __builtin_amdgcn_s_setprio(1);
#pragma unroll
    for (int ks = 0; ks < 4; ++ks) {
      bf16x8 v0 = *(const bf16x8*)(Vb_ + (ks * 2 + 0) * 512 + l * 8);
      bf16x8 v1 = *(const bf16x8*)(Vb_ + (ks * 2 + 1) * 512 + l * 8);
      O0 = __builtin_amdgcn_mfma_f32_32x32x16_bf16(v0, pb[ks], O0, 0, 0, 0);
      O1 = __builtin_amdgcn_mfma_f32_32x32x16_bf16(v1, pb[ks], O1, 0, 0, 0);
    }
    __builtin_amdgcn_s_setprio(0);
  };

  f32x16 scA0, scA1, scB0, scB1;
  u16* pA = &KVbuf[0][0];
  u16* pB = &KVbuf[1][0];
  u16* pC = &KVbuf[2][0];
  u16* pD = &KVbuf[3][0];
  // prologue: stage tiles 0..2 (qf loads are oldest in the VMEM queue)
  stageKV(0, pA);
  stageKV(1, pB);
  stageKV(2, pC);
  asm volatile("s_waitcnt vmcnt(4)" ::: "memory");   // qf,KV0,KV1 landed; KV2 fly
  __builtin_amdgcn_s_barrier();
  __builtin_amdgcn_sched_barrier(0);
  qk_lds(pA, scA0, scA1);                            // scores for tile 0
#pragma unroll 1
  for (int dt = 0; dt < 16; ++dt) {
    const int t = dt * 2;
    {   // sub-iter t: scores(t) in scA; QK(t+1) -> scB; sm_pv(t) from pA's V
      if (t < 30) asm volatile("s_waitcnt vmcnt(4)" ::: "memory");
      else        asm volatile("s_waitcnt vmcnt(0)" ::: "memory");
      __builtin_amdgcn_s_barrier();
      __builtin_amdgcn_sched_barrier(0);
      if (t + 3 < 32) stageKV(t + 3, pD);  // pD: last read at sub-iter t-1
      qk_lds(pB, scB0, scB1);              // tile t+1 landed per vmcnt above
      sm_pv(pA + 4096, scA0, scA1);
    }
    {   // sub-iter t+1: scores in scB; QK(t+2) -> scA; sm_pv(t+1) from pB's V
      if (t + 1 < 30) asm volatile("s_waitcnt vmcnt(4)" ::: "memory");
      else            asm volatile("s_waitcnt vmcnt(0)" ::: "memory");
      __builtin_amdgcn_s_barrier();
      __builtin_amdgcn_sched_barrier(0);
      if (t + 4 < 32) stageKV(t + 4, pA);  // pA: last read this even sub-iter
      if (t + 2 < 32) qk_lds(pC, scA0, scA1);
      sm_pv(pB + 4096, scB0, scB1);
    }
    u16* t1 = pA; pA = pC; pC = t1;        // rotate ring by 2
    u16* t2 = pB; pB = pD; pD = t2;
  }
  float inv = 1.0f / lsum;
  const int q0 = qt * 128 + w * 32;
  const size_t rowoff = ((size_t)(b * 2048 + q0 + lq)) * 1024 + h * 64;
#pragma unroll
  for (int g = 0; g < 4; ++g) {                 // hd = 8g + 4hi + rr (+32 for O1)
    u16x4 oa, ob;
#pragma unroll
    for (int rr = 0; rr < 4; ++rr) {
      oa[rr] = f2bf(O0[4 * g + rr] * inv);
      ob[rr] = f2bf(O1[4 * g + rr] * inv);
    }
    *(u16x4*)(ctx + rowoff + 8 * g + 4 * hi) = oa;
    *(u16x4*)(ctx + rowoff + 32 + 8 * g + 4 * hi) = ob;
  }
}

// ---------------------------------------------------------------- launch
extern "C" void kernel_launch(void* const* d_in, const int* in_sizes, int n_in,
                              void* d_out, int out_size, void* d_ws, size_t ws_size,
                              hipStream_t stream) {
  (void)in_sizes; (void)n_in; (void)out_size; (void)ws_size;
  const float* x  = (const float*)d_in[0];
  const float* Wq = (const float*)d_in[1];
  const float* bq = (const float*)d_in[2];
  const float* Wk = (const float*)d_in[3];
  const float* bk = (const float*)d_in[4];
  const float* Wv = (const float*)d_in[5];
  const float* bv = (const float*)d_in[6];
  const float* Wo = (const float*)d_in[7];
  const float* bo = (const float*)d_in[8];
  const float* gq = (const float*)d_in[9];
  const float* gk = (const float*)d_in[10];
  const float* fc = (const float*)d_in[11];
  const float* fs = (const float*)d_in[12];
  float* out = (float*)d_out;
  char* ws = (char*)d_ws;
  u16*  xb  = (u16*)(ws + 0);           //  8 MB  x bf16 [4096][1024]
  u16*  wqb = (u16*)(ws + 8388608);     //  2 MB each, contiguous x4
  u16*  wkb = (u16*)(ws + 10485760);
  u16*  wvb = (u16*)(ws + 12582912);
  u16*  wob = (u16*)(ws + 14680064);
  u16*  Qfb = (u16*)(ws + 16777216);    //  8 MB bf16 pre-norm q rows
  u16*  Kfb = (u16*)(ws + 25165824);    //  8 MB pre-norm k rows
  u16*  Qfr = (u16*)(ws + 33554432);    //  8 MB Q fragment-major
  u16*  Kfr = (u16*)(ws + 41943040);    //  8 MB K fragment-major (row-permuted)
  u16*  Vfr = (u16*)(ws + 50331648);    //  8 MB V fragment-major
  u16*  ctx = (u16*)(ws + 58720256);    //  8 MB bf16 [B,S,D]

  f2ball_kernel<<<8192, 256, 0, stream>>>(x, Wq, Wk, Wv, Wo, xb, wqb);
  qkv_gemm<<<dim3(32, 8, 3), 256, 0, stream>>>(xb, wqb, wkb, wvb, bq, bk, bv, Qfb, Kfb, Vfr);
  rmsrope<<<dim3(4096, 2), 256, 0, stream>>>(Qfb, Kfb, gq, gk, fc, fs, Qfr, Kfr);
  attn_kernel<<<512, 256, 0, stream>>>(Qfr, Kfr, Vfr, ctx);
  proj_gemm<<<dim3(64, 8), 256, 0, stream>>>(ctx, wob, bo, out);
}